// Round 8
// baseline (113.572 us; speedup 1.0000x reference)
//
#include <hip/hip_runtime.h>
#include <stdint.h>

#define Bb 8
#define Ll 2048
#define Ss 2048
#define Dd 128
#define NSB 8
#define SCHUNK 256
#define NROWS 16384  // Bb*Ll == Bb*Ss
#define SCALE_LOG2E 92.33248261689366f  // 64 * log2(e); also the fixed softmax max

typedef __attribute__((ext_vector_type(8))) short bf16x8;
typedef __attribute__((ext_vector_type(16))) float f32x16;

__device__ __forceinline__ unsigned f2bf_pack(float a, float b) {
  unsigned ua = __float_as_uint(a); ua += 0x7fffu + ((ua >> 16) & 1u);
  unsigned ub = __float_as_uint(b); ub += 0x7fffu + ((ub >> 16) & 1u);
  return (ua >> 16) | (ub & 0xffff0000u);
}

__device__ __forceinline__ unsigned pkbf(float a, float b) {
#if __has_builtin(__builtin_amdgcn_cvt_pk_bf16_f32)
  auto r = __builtin_amdgcn_cvt_pk_bf16_f32(a, b);
  return __builtin_bit_cast(unsigned, r);
#else
  return f2bf_pack(a, b);
#endif
}

__device__ __forceinline__ void gl_lds16(const void* g, void* l) {
  __builtin_amdgcn_global_load_lds(
      (const __attribute__((address_space(1))) unsigned*)g,
      (__attribute__((address_space(3))) unsigned*)l, 16, 0, 0);
}

// Fragment-major layouts, per 32-s block = 8 slots * 1 KB = 8 KB (4096 ushort):
//  Kf slot kt, lane l=(h*32+s): K[s][d=kt*16+h*8+j], j=0..7
//  Vf slot (dblk*2+t2), lane l=(h*32+dloc): V^T[d=dblk*32+dloc][s_perm]
//    s_perm = t2*16 + 4*h + (j&3) + 8*(j>>2)  == S-MFMA C-reg order, so the
//    P B-fragment is just consecutive acc registers (no shuffles).

// ---------------- pre-pass (identical to R7, verified) ----------------
extern "C" __global__ __launch_bounds__(256)
void prep_kern(const float* __restrict__ Q, const float* __restrict__ K,
               const float* __restrict__ V,
               unsigned short* __restrict__ Qn, unsigned short* __restrict__ Kf,
               unsigned short* __restrict__ Vf) {
  __shared__ float Tf[32 * 130];
  __shared__ float Ps[32 * 8];
  __shared__ float Nr[32];
  __shared__ unsigned short Tb[32 * 128];
  const int t = threadIdx.x;
  const int bid = blockIdx.x;
  if (bid < 4096) {  // Q: one row per wave, row-major bf16 out
    const int lane = t & 63;
    const int r = bid * 4 + (t >> 6);
    float2 f = *(const float2*)(Q + (size_t)r * Dd + lane * 2);
    float ss = f.x * f.x + f.y * f.y;
#pragma unroll
    for (int m = 1; m < 64; m <<= 1) ss += __shfl_xor(ss, m, 64);
    float inv = 1.0f / fmaxf(sqrtf(ss), 1e-12f);
    *(unsigned*)(Qn + (size_t)r * Dd + lane * 2) = pkbf(f.x * inv, f.y * inv);
  } else if (bid < 4608) {  // K: 32-row block -> normalize -> frag-major
    const int kb = bid - 4096;
    const int b = kb & 7, sw = kb >> 3;
    const int sl = t >> 3, d0 = (t & 7) * 16;
    const float* src = K + ((size_t)(b * Ss + sw * 32 + sl)) * Dd + d0;
    float ss = 0.f;
#pragma unroll
    for (int i = 0; i < 4; ++i) {
      float4 v = *(const float4*)(src + i * 4);
      Tf[sl * 130 + d0 + i * 4 + 0] = v.x;
      Tf[sl * 130 + d0 + i * 4 + 1] = v.y;
      Tf[sl * 130 + d0 + i * 4 + 2] = v.z;
      Tf[sl * 130 + d0 + i * 4 + 3] = v.w;
      ss += v.x * v.x + v.y * v.y + v.z * v.z + v.w * v.w;
    }
    Ps[sl * 8 + (t & 7)] = ss;
    __syncthreads();
    if (t < 32) {
      float s = 0.f;
#pragma unroll
      for (int j = 0; j < 8; ++j) s += Ps[t * 8 + j];
      Nr[t] = 1.0f / fmaxf(sqrtf(s), 1e-12f);
    }
    __syncthreads();
    unsigned short* Ko = Kf + ((size_t)(b * 64 + sw)) * 4096;
#pragma unroll
    for (int p = 0; p < 2; ++p) {
      const int run = p * 256 + t;
      const int lane = run & 63, s = lane & 31, h = lane >> 5;
      const int d = (run >> 6) * 16 + h * 8;
      const float n = Nr[s];
      const float* row = &Tf[s * 130 + d];
      uint4 w;
      w.x = pkbf(row[0] * n, row[1] * n);
      w.y = pkbf(row[2] * n, row[3] * n);
      w.z = pkbf(row[4] * n, row[5] * n);
      w.w = pkbf(row[6] * n, row[7] * n);
      *(uint4*)(Ko + run * 8) = w;
    }
  } else {  // V: 32-row block -> transpose -> j-permuted frag-major
    const int vb = bid - 4608;
    const int b = vb & 7, sw = vb >> 3;
    const int sl = t >> 3, d0 = (t & 7) * 16;
    const float* src = V + ((size_t)(b * Ss + sw * 32 + sl)) * Dd + d0;
#pragma unroll
    for (int i = 0; i < 4; ++i) {
      float4 v = *(const float4*)(src + i * 4);
      *(unsigned*)&Tb[sl * 128 + d0 + i * 4]     = pkbf(v.x, v.y);
      *(unsigned*)&Tb[sl * 128 + d0 + i * 4 + 2] = pkbf(v.z, v.w);
    }
    __syncthreads();
    unsigned short* Vo = Vf + ((size_t)(b * 64 + sw)) * 4096;
#pragma unroll
    for (int p = 0; p < 2; ++p) {
      const int run = p * 256 + t;
      const int vslot = run >> 6, lane = run & 63;
      const int dloc = lane & 31, h = lane >> 5;
      const int dblk = vslot >> 1, t2 = vslot & 1;
      const int d = dblk * 32 + dloc;
      unsigned short w[8];
#pragma unroll
      for (int j = 0; j < 8; ++j) {
        const int sloc = t2 * 16 + 4 * h + (j & 3) + 8 * (j >> 2);
        w[j] = Tb[sloc * 128 + d];
      }
      *(uint4*)(Vo + run * 8) = *(uint4*)w;
    }
  }
}

// ---------------- main fused attention: 2 m-tiles per wave ----------------
// grid 1024: gid = qt*64 + b*8 + sb; WG = 2 waves (128 thr), wave owns 64
// q-rows (two 32-row m-tiles) -> each K/V LDS fragment read feeds 2 MFMAs,
// halving LDS-pipe pressure; acc0/acc1 are independent MFMA dep-chains.
// SCHUNK 256, 32-s tile, K+V LDS 16 KB dbuf = 32 KB/WG -> 4 WG/CU.
extern "C" __global__ __launch_bounds__(128, 2)
void attn_kern(const unsigned short* __restrict__ Qn,
               const unsigned short* __restrict__ Kf,
               const unsigned short* __restrict__ Vf,
               unsigned short* __restrict__ Op,
               float* __restrict__ Lp) {
  __shared__ unsigned short Kl[2][8 * 512];
  __shared__ unsigned short Vl[2][8 * 512];
  const int tid = threadIdx.x, wv = tid >> 6, lane = tid & 63;
  const int lm = lane & 31, h = lane >> 5;
  const int gid = blockIdx.x;
  const int qt = gid >> 6, b = (gid >> 3) & 7, sb = gid & 7;
  const int sblk0 = sb * (SCHUNK / 32);
  const int qrow = qt * 128 + wv * 64 + lm;  // m-tile0; m-tile1 = +32

  // Q B-fragments for both m-tiles (held in registers all kernel)
  bf16x8 qf0[8], qf1[8];
  {
    const unsigned short* Qr0 = Qn + ((size_t)(b * Ll + qrow)) * Dd;
#pragma unroll
    for (int kt = 0; kt < 8; ++kt) {
      qf0[kt] = *(const bf16x8*)(Qr0 + kt * 16 + h * 8);
      qf1[kt] = *(const bf16x8*)(Qr0 + 32 * Dd + kt * 16 + h * 8);
    }
  }
  const unsigned short* Kc = Kf + ((size_t)(b * 64 + sblk0)) * 4096;
  const unsigned short* Vc = Vf + ((size_t)(b * 64 + sblk0)) * 4096;

  f32x16 o0[4], o1[4];
#pragma unroll
  for (int i = 0; i < 4; ++i)
#pragma unroll
    for (int r = 0; r < 16; ++r) { o0[i][r] = 0.f; o1[i][r] = 0.f; }

  auto stage = [&](int it, int buf) {
#pragma unroll
    for (int i = 0; i < 8; ++i) {  // wave0 -> K slots, wave1 -> V slots
      if (wv == 0)
        gl_lds16(Kc + (size_t)it * 4096 + i * 512 + lane * 8, &Kl[buf][i * 512]);
      else
        gl_lds16(Vc + (size_t)it * 4096 + i * 512 + lane * 8, &Vl[buf][i * 512]);
    }
  };
  stage(0, 0);

  float l0 = 0.f, l1 = 0.f;

#pragma unroll 1
  for (int it = 0; it < 8; ++it) {
    __syncthreads();  // drains vmcnt: cur staged; prev buffer reads done
    const int cur = it & 1;
    if (it + 1 < 8) stage(it + 1, cur ^ 1);

    // S^T = K · Q^T for both m-tiles: one K-frag read -> 2 MFMAs,
    // two independent accumulator chains.
    f32x16 a0, a1;
#pragma unroll
    for (int r = 0; r < 16; ++r) { a0[r] = 0.f; a1[r] = 0.f; }
#pragma unroll
    for (int kt = 0; kt < 8; ++kt) {
      bf16x8 kf = *(const bf16x8*)&Kl[cur][kt * 512 + lane * 8];
      a0 = __builtin_amdgcn_mfma_f32_32x32x16_bf16(kf, qf0[kt], a0, 0, 0, 0);
      a1 = __builtin_amdgcn_mfma_f32_32x32x16_bf16(kf, qf1[kt], a1, 0, 0, 0);
    }

    // fixed-max softmax; P B-frag = consecutive acc regs (j-permuted Vf)
#pragma unroll
    for (int t2 = 0; t2 < 2; ++t2) {
      float p0[8], p1[8];
#pragma unroll
      for (int j = 0; j < 8; ++j) {
        p0[j] = __builtin_amdgcn_exp2f(
            __builtin_fmaf(a0[t2 * 8 + j], SCALE_LOG2E, -SCALE_LOG2E));
        p1[j] = __builtin_amdgcn_exp2f(
            __builtin_fmaf(a1[t2 * 8 + j], SCALE_LOG2E, -SCALE_LOG2E));
      }
      l0 += ((p0[0] + p0[1]) + (p0[2] + p0[3])) + ((p0[4] + p0[5]) + (p0[6] + p0[7]));
      l1 += ((p1[0] + p1[1]) + (p1[2] + p1[3])) + ((p1[4] + p1[5]) + (p1[6] + p1[7]));
      uint4 f0, f1;
      f0.x = pkbf(p0[0], p0[1]); f0.y = pkbf(p0[2], p0[3]);
      f0.z = pkbf(p0[4], p0[5]); f0.w = pkbf(p0[6], p0[7]);
      f1.x = pkbf(p1[0], p1[1]); f1.y = pkbf(p1[2], p1[3]);
      f1.z = pkbf(p1[4], p1[5]); f1.w = pkbf(p1[6], p1[7]);
      bf16x8 pf0 = __builtin_bit_cast(bf16x8, f0);
      bf16x8 pf1 = __builtin_bit_cast(bf16x8, f1);
      // O^T += V^T · P^T : one V-frag read -> 2 MFMAs
#pragma unroll
      for (int dblk = 0; dblk < 4; ++dblk) {
        bf16x8 vf = *(const bf16x8*)&Vl[cur][(dblk * 2 + t2) * 512 + lane * 8];
        o0[dblk] = __builtin_amdgcn_mfma_f32_32x32x16_bf16(vf, pf0, o0[dblk], 0, 0, 0);
        o1[dblk] = __builtin_amdgcn_mfma_f32_32x32x16_bf16(vf, pf1, o1[dblk], 0, 0, 0);
      }
    }
  }

  // epilogue: partial (unnormalized) O bf16 + per-row l (shared fixed max)
  const float lt0 = l0 + __shfl_xor(l0, 32, 64);
  const float lt1 = l1 + __shfl_xor(l1, 32, 64);
  unsigned short* Ob0 = Op + ((size_t)sb * NROWS + b * Ll + qrow) * Dd;
#pragma unroll
  for (int dblk = 0; dblk < 4; ++dblk)
#pragma unroll
    for (int g = 0; g < 4; ++g) {
      uint2 w0, w1;
      w0.x = pkbf(o0[dblk][g * 4 + 0], o0[dblk][g * 4 + 1]);
      w0.y = pkbf(o0[dblk][g * 4 + 2], o0[dblk][g * 4 + 3]);
      w1.x = pkbf(o1[dblk][g * 4 + 0], o1[dblk][g * 4 + 1]);
      w1.y = pkbf(o1[dblk][g * 4 + 2], o1[dblk][g * 4 + 3]);
      *(uint2*)(Ob0 + dblk * 32 + g * 8 + h * 4) = w0;           // m-tile0
      *(uint2*)(Ob0 + (size_t)32 * Dd + dblk * 32 + g * 8 + h * 4) = w1;  // m-tile1
    }
  if (h == 0) {
    Lp[sb * NROWS + b * Ll + qrow] = lt0;
    Lp[sb * NROWS + b * Ll + qrow + 32] = lt1;
  }
}

// ---------------- combine the NSB S-chunk partials (pure sum: shared max) ---
extern "C" __global__ __launch_bounds__(256)
void comb_kern(const unsigned short* __restrict__ Op,
               const float* __restrict__ Lp, float* __restrict__ Out) {
  const int idx = blockIdx.x * 256 + threadIdx.x;  // one thread per 4 d
  const int row = idx >> 5;
  const int dof = (idx & 31) * 4;
  float den = 0.f;
#pragma unroll
  for (int s = 0; s < NSB; ++s) den += Lp[s * NROWS + row];
  float a0 = 0.f, a1 = 0.f, a2 = 0.f, a3 = 0.f;
#pragma unroll
  for (int s = 0; s < NSB; ++s) {
    uint2 v = *(const uint2*)(Op + ((size_t)s * NROWS + row) * Dd + dof);
    a0 += __uint_as_float(v.x << 16);
    a1 += __uint_as_float(v.x & 0xffff0000u);
    a2 += __uint_as_float(v.y << 16);
    a3 += __uint_as_float(v.y & 0xffff0000u);
  }
  const float inv = 1.f / den;
  float4 r; r.x = a0 * inv; r.y = a1 * inv; r.z = a2 * inv; r.w = a3 * inv;
  *(float4*)(Out + (size_t)row * Dd + dof) = r;
}

extern "C" void kernel_launch(void* const* d_in, const int* in_sizes, int n_in,
                              void* d_out, int out_size, void* d_ws, size_t ws_size,
                              hipStream_t stream) {
  const float* Q = (const float*)d_in[0];
  const float* K = (const float*)d_in[1];
  const float* V = (const float*)d_in[2];
  float* Out = (float*)d_out;
  unsigned short* Qn = (unsigned short*)d_ws;                  // 4 MiB
  unsigned short* Kf = Qn + (size_t)NROWS * Dd;                // 4 MiB (frag-major)
  unsigned short* Vf = Kf + (size_t)NROWS * Dd;                // 4 MiB (frag-major, j-permuted)
  unsigned short* Op = Vf + (size_t)Bb * Dd * Ss;              // 32 MiB (bf16 partials)
  float* Lp = (float*)(Op + (size_t)NSB * NROWS * Dd);         // 512 KiB
  hipLaunchKernelGGL(prep_kern, dim3(4096 + 512 + 512), dim3(256), 0, stream,
                     Q, K, V, Qn, Kf, Vf);
  hipLaunchKernelGGL(attn_kern, dim3(1024), dim3(128), 0, stream, Qn, Kf, Vf, Op, Lp);
  hipLaunchKernelGGL(comb_kern, dim3(2048), dim3(256), 0, stream, Op, Lp, Out);
}

// Round 9
// 106.422 us; speedup vs baseline: 1.0672x; 1.0672x over previous
//
#include <hip/hip_runtime.h>
#include <stdint.h>

#define Bb 8
#define Ll 2048
#define Ss 2048
#define Dd 128
#define NSB 4
#define SCHUNK 512
#define NROWS 16384  // Bb*Ll == Bb*Ss
#define SCALE_LOG2E 92.33248261689366f  // 64 * log2(e); also the fixed softmax max

typedef __attribute__((ext_vector_type(8))) short bf16x8;
typedef __attribute__((ext_vector_type(16))) float f32x16;

__device__ __forceinline__ unsigned f2bf_pack(float a, float b) {
  unsigned ua = __float_as_uint(a); ua += 0x7fffu + ((ua >> 16) & 1u);
  unsigned ub = __float_as_uint(b); ub += 0x7fffu + ((ub >> 16) & 1u);
  return (ua >> 16) | (ub & 0xffff0000u);
}

__device__ __forceinline__ unsigned pkbf(float a, float b) {
#if __has_builtin(__builtin_amdgcn_cvt_pk_bf16_f32)
  auto r = __builtin_amdgcn_cvt_pk_bf16_f32(a, b);
  return __builtin_bit_cast(unsigned, r);
#else
  return f2bf_pack(a, b);
#endif
}

__device__ __forceinline__ void gl_lds16(const void* g, void* l) {
  __builtin_amdgcn_global_load_lds(
      (const __attribute__((address_space(1))) unsigned*)g,
      (__attribute__((address_space(3))) unsigned*)l, 16, 0, 0);
}

// Fragment-major layouts, per 32-s block = 8 slots * 1 KB = 8 KB (4096 ushort):
//  Kf slot kt, lane l=(h*32+s): K[s][d=kt*16+h*8+j], j=0..7
//  Vf slot (dblk*2+t2), lane l=(h*32+dloc): V^T[d=dblk*32+dloc][s_perm]
//    s_perm = t2*16 + 4*h + (j&3) + 8*(j>>2)  == S-MFMA C-reg order, so the
//    P B-fragment is just consecutive acc registers (no shuffles).

// ---------------- pre-pass (identical to R7, verified) ----------------
extern "C" __global__ __launch_bounds__(256)
void prep_kern(const float* __restrict__ Q, const float* __restrict__ K,
               const float* __restrict__ V,
               unsigned short* __restrict__ Qn, unsigned short* __restrict__ Kf,
               unsigned short* __restrict__ Vf) {
  __shared__ float Tf[32 * 130];
  __shared__ float Ps[32 * 8];
  __shared__ float Nr[32];
  __shared__ unsigned short Tb[32 * 128];
  const int t = threadIdx.x;
  const int bid = blockIdx.x;
  if (bid < 4096) {  // Q: one row per wave, row-major bf16 out
    const int lane = t & 63;
    const int r = bid * 4 + (t >> 6);
    float2 f = *(const float2*)(Q + (size_t)r * Dd + lane * 2);
    float ss = f.x * f.x + f.y * f.y;
#pragma unroll
    for (int m = 1; m < 64; m <<= 1) ss += __shfl_xor(ss, m, 64);
    float inv = 1.0f / fmaxf(sqrtf(ss), 1e-12f);
    *(unsigned*)(Qn + (size_t)r * Dd + lane * 2) = pkbf(f.x * inv, f.y * inv);
  } else if (bid < 4608) {  // K: 32-row block -> normalize -> frag-major
    const int kb = bid - 4096;
    const int b = kb & 7, sw = kb >> 3;
    const int sl = t >> 3, d0 = (t & 7) * 16;
    const float* src = K + ((size_t)(b * Ss + sw * 32 + sl)) * Dd + d0;
    float ss = 0.f;
#pragma unroll
    for (int i = 0; i < 4; ++i) {
      float4 v = *(const float4*)(src + i * 4);
      Tf[sl * 130 + d0 + i * 4 + 0] = v.x;
      Tf[sl * 130 + d0 + i * 4 + 1] = v.y;
      Tf[sl * 130 + d0 + i * 4 + 2] = v.z;
      Tf[sl * 130 + d0 + i * 4 + 3] = v.w;
      ss += v.x * v.x + v.y * v.y + v.z * v.z + v.w * v.w;
    }
    Ps[sl * 8 + (t & 7)] = ss;
    __syncthreads();
    if (t < 32) {
      float s = 0.f;
#pragma unroll
      for (int j = 0; j < 8; ++j) s += Ps[t * 8 + j];
      Nr[t] = 1.0f / fmaxf(sqrtf(s), 1e-12f);
    }
    __syncthreads();
    unsigned short* Ko = Kf + ((size_t)(b * 64 + sw)) * 4096;
#pragma unroll
    for (int p = 0; p < 2; ++p) {
      const int run = p * 256 + t;
      const int lane = run & 63, s = lane & 31, h = lane >> 5;
      const int d = (run >> 6) * 16 + h * 8;
      const float n = Nr[s];
      const float* row = &Tf[s * 130 + d];
      uint4 w;
      w.x = pkbf(row[0] * n, row[1] * n);
      w.y = pkbf(row[2] * n, row[3] * n);
      w.z = pkbf(row[4] * n, row[5] * n);
      w.w = pkbf(row[6] * n, row[7] * n);
      *(uint4*)(Ko + run * 8) = w;
    }
  } else {  // V: 32-row block -> transpose -> j-permuted frag-major
    const int vb = bid - 4608;
    const int b = vb & 7, sw = vb >> 3;
    const int sl = t >> 3, d0 = (t & 7) * 16;
    const float* src = V + ((size_t)(b * Ss + sw * 32 + sl)) * Dd + d0;
#pragma unroll
    for (int i = 0; i < 4; ++i) {
      float4 v = *(const float4*)(src + i * 4);
      *(unsigned*)&Tb[sl * 128 + d0 + i * 4]     = pkbf(v.x, v.y);
      *(unsigned*)&Tb[sl * 128 + d0 + i * 4 + 2] = pkbf(v.z, v.w);
    }
    __syncthreads();
    unsigned short* Vo = Vf + ((size_t)(b * 64 + sw)) * 4096;
#pragma unroll
    for (int p = 0; p < 2; ++p) {
      const int run = p * 256 + t;
      const int vslot = run >> 6, lane = run & 63;
      const int dloc = lane & 31, h = lane >> 5;
      const int dblk = vslot >> 1, t2 = vslot & 1;
      const int d = dblk * 32 + dloc;
      unsigned short w[8];
#pragma unroll
      for (int j = 0; j < 8; ++j) {
        const int sloc = t2 * 16 + 4 * h + (j & 3) + 8 * (j >> 2);
        w[j] = Tb[sloc * 128 + d];
      }
      *(uint4*)(Vo + run * 8) = *(uint4*)w;
    }
  }
}

// ---------------- main fused attention: vmcnt-gated ring pipeline ----------
// grid 512: gid = qt*32 + b*4 + sb; 4 waves, 32 q-rows each; SCHUNK=512,
// 16 iters of 32-s tiles. 4-deep LDS ring (64 KB), staged at distance 2;
// per-iter gate = `s_waitcnt vmcnt(4); s_barrier` (raw) so the barrier
// NEVER drains in-flight prefetches (the __syncthreads vmcnt(0) stall).
extern "C" __global__ __launch_bounds__(256, 2)
void attn_kern(const unsigned short* __restrict__ Qn,
               const unsigned short* __restrict__ Kf,
               const unsigned short* __restrict__ Vf,
               unsigned short* __restrict__ Op,
               float* __restrict__ Lp) {
  __shared__ unsigned short Kl[4][8 * 512];  // 4-ring of 8-slot (8 KB) K tiles
  __shared__ unsigned short Vl[4][8 * 512];
  const int tid = threadIdx.x, wv = tid >> 6, lane = tid & 63;
  const int lm = lane & 31, h = lane >> 5;
  const int gid = blockIdx.x;
  const int qt = gid >> 5, b = (gid >> 2) & 7, sb = gid & 3;
  const int sblk0 = sb * (SCHUNK / 32);
  const int qrow = qt * 128 + wv * 32 + lm;

  // Q B-fragments (k = d): registers for whole kernel (oldest vmem ops)
  const unsigned short* Qrow = Qn + ((size_t)(b * Ll + qrow)) * Dd;
  bf16x8 qf[8];
#pragma unroll
  for (int kt = 0; kt < 8; ++kt)
    qf[kt] = *(const bf16x8*)(Qrow + kt * 16 + h * 8);

  const unsigned short* Kc = Kf + ((size_t)(b * 64 + sblk0)) * 4096;
  const unsigned short* Vc = Vf + ((size_t)(b * 64 + sblk0)) * 4096;

  f32x16 o[4];
#pragma unroll
  for (int i = 0; i < 4; ++i)
#pragma unroll
    for (int r = 0; r < 16; ++r) o[i][r] = 0.f;

  // stage tile t into ring slot r: 4 gl_lds16 per wave (2 K + 2 V)
  auto stage = [&](int t, int r) {
    const unsigned short* kb = Kc + (size_t)t * 4096;
    const unsigned short* vb = Vc + (size_t)t * 4096;
#pragma unroll
    for (int i = 0; i < 2; ++i) {
      const int sl = wv * 2 + i;
      gl_lds16(kb + sl * 512 + lane * 8, &Kl[r][sl * 512]);
      gl_lds16(vb + sl * 512 + lane * 8, &Vl[r][sl * 512]);
    }
  };
  stage(0, 0);
  stage(1, 1);

  float lrun = 0.f;

#pragma unroll 1
  for (int it = 0; it < 16; ++it) {
    // Gate: batch(it) complete (<=4 outstanding leaves only batch(it+1)
    // in flight), then converge. No vmcnt(0) drain except the final tile.
    if (it < 15)
      asm volatile("s_waitcnt vmcnt(4)\n\ts_barrier" ::: "memory");
    else
      asm volatile("s_waitcnt vmcnt(0)\n\ts_barrier" ::: "memory");
    const int r = it & 3;
    if (it + 2 < 16) stage(it + 2, (it + 2) & 3);

    // S^T = K · Q^T  (M=s 32, N=m 32, K=d 8x16)
    f32x16 acc;
#pragma unroll
    for (int rr = 0; rr < 16; ++rr) acc[rr] = 0.f;
#pragma unroll
    for (int kt = 0; kt < 8; ++kt) {
      bf16x8 kf = *(const bf16x8*)&Kl[r][kt * 512 + lane * 8];
      acc = __builtin_amdgcn_mfma_f32_32x32x16_bf16(kf, qf[kt], acc, 0, 0, 0);
    }
    // fixed-max softmax; P B-frag = consecutive acc regs (j-permuted Vf)
#pragma unroll
    for (int t2 = 0; t2 < 2; ++t2) {
      float p[8];
#pragma unroll
      for (int j = 0; j < 8; ++j)
        p[j] = __builtin_amdgcn_exp2f(
            __builtin_fmaf(acc[t2 * 8 + j], SCALE_LOG2E, -SCALE_LOG2E));
      lrun += ((p[0] + p[1]) + (p[2] + p[3])) + ((p[4] + p[5]) + (p[6] + p[7]));
      uint4 fr;
      fr.x = pkbf(p[0], p[1]);
      fr.y = pkbf(p[2], p[3]);
      fr.z = pkbf(p[4], p[5]);
      fr.w = pkbf(p[6], p[7]);
      bf16x8 pf = __builtin_bit_cast(bf16x8, fr);
      // O^T += V^T · P^T  (M=d 4x32, N=m 32, K=s 16, s-order pre-permuted)
#pragma unroll
      for (int dblk = 0; dblk < 4; ++dblk) {
        bf16x8 vf = *(const bf16x8*)&Vl[r][(dblk * 2 + t2) * 512 + lane * 8];
        o[dblk] = __builtin_amdgcn_mfma_f32_32x32x16_bf16(vf, pf, o[dblk], 0, 0, 0);
      }
    }
  }

  // epilogue: partial (unnormalized) O bf16 + per-row l (shared fixed max)
  const float lt = lrun + __shfl_xor(lrun, 32, 64);
  unsigned short* Ob = Op + ((size_t)sb * NROWS + b * Ll + qrow) * Dd;
#pragma unroll
  for (int dblk = 0; dblk < 4; ++dblk)
#pragma unroll
    for (int g = 0; g < 4; ++g) {
      uint2 w;
      w.x = pkbf(o[dblk][g * 4 + 0], o[dblk][g * 4 + 1]);
      w.y = pkbf(o[dblk][g * 4 + 2], o[dblk][g * 4 + 3]);
      *(uint2*)(Ob + dblk * 32 + g * 8 + h * 4) = w;  // d = 32*dblk + 8*g + 4*h
    }
  if (h == 0) Lp[sb * NROWS + b * Ll + qrow] = lt;
}

// ---------------- combine the NSB S-chunk partials (pure sum: shared max) ---
extern "C" __global__ __launch_bounds__(256)
void comb_kern(const unsigned short* __restrict__ Op,
               const float* __restrict__ Lp, float* __restrict__ Out) {
  const int idx = blockIdx.x * 256 + threadIdx.x;  // one thread per 4 d
  const int row = idx >> 5;
  const int dof = (idx & 31) * 4;
  float den = 0.f;
#pragma unroll
  for (int s = 0; s < NSB; ++s) den += Lp[s * NROWS + row];
  float a0 = 0.f, a1 = 0.f, a2 = 0.f, a3 = 0.f;
#pragma unroll
  for (int s = 0; s < NSB; ++s) {
    uint2 v = *(const uint2*)(Op + ((size_t)s * NROWS + row) * Dd + dof);
    a0 += __uint_as_float(v.x << 16);
    a1 += __uint_as_float(v.x & 0xffff0000u);
    a2 += __uint_as_float(v.y << 16);
    a3 += __uint_as_float(v.y & 0xffff0000u);
  }
  const float inv = 1.f / den;
  float4 r; r.x = a0 * inv; r.y = a1 * inv; r.z = a2 * inv; r.w = a3 * inv;
  *(float4*)(Out + (size_t)row * Dd + dof) = r;
}

extern "C" void kernel_launch(void* const* d_in, const int* in_sizes, int n_in,
                              void* d_out, int out_size, void* d_ws, size_t ws_size,
                              hipStream_t stream) {
  const float* Q = (const float*)d_in[0];
  const float* K = (const float*)d_in[1];
  const float* V = (const float*)d_in[2];
  float* Out = (float*)d_out;
  unsigned short* Qn = (unsigned short*)d_ws;                  // 4 MiB
  unsigned short* Kf = Qn + (size_t)NROWS * Dd;                // 4 MiB (frag-major)
  unsigned short* Vf = Kf + (size_t)NROWS * Dd;                // 4 MiB (frag-major, j-permuted)
  unsigned short* Op = Vf + (size_t)Bb * Dd * Ss;              // 16 MiB (bf16 partials)
  float* Lp = (float*)(Op + (size_t)NSB * NROWS * Dd);         // 256 KiB
  hipLaunchKernelGGL(prep_kern, dim3(4096 + 512 + 512), dim3(256), 0, stream,
                     Q, K, V, Qn, Kf, Vf);
  hipLaunchKernelGGL(attn_kern, dim3(512), dim3(256), 0, stream, Qn, Kf, Vf, Op, Lp);
  hipLaunchKernelGGL(comb_kern, dim3(2048), dim3(256), 0, stream, Op, Lp, Out);
}